// Round 16
// baseline (109.582 us; speedup 1.0000x reference)
//
#include <hip/hip_runtime.h>
#include <hip/hip_bf16.h>
#include <math.h>

// Averaged Hausdorff distance between two 16384x3 fp32 point sets.
// R15 post-mortem: symmetric single-pass LOST (58.9 vs 46.2): shfl butterfly
// (dependent DS-pipe chain) + 16.6MB of contended global atomicMin traffic +
// extra adds ate the halved FMA work. Also: gap=48.9us at 132KB ws proves
// poison is NOT per-used-MB; R14's 74.7 gap was its low-parallelism reduce.
// R16 = directed store pipeline (R14's proven pair form) with:
//   (a) 2048 blocks (P=8, XBLK=8) = 8 blocks/CU under launch_bounds(256,4)
//       -- tests the last occupancy doubling (R13: 2->4 blocks/CU = -11%).
//   (b) 2-stage parallel reduce: 512-block y-slice min -> 64-block sqrt+sum.
//       No atomics anywhere, no init kernel.

#define NPTS   16384
#define BLK    256
#define P      8                    // outer points per thread
#define CHUNK  128                  // inner points per LDS tile
#define XBLK   (NPTS / (BLK * P))   // 8
#define SPLIT  (NPTS / CHUNK)       // 128
#define NSLICE 4                    // reduce stage-1 output slices per dir
#define YSL    (SPLIT / NSLICE)     // 32 y per slice
#define FLTMAX 3.402823466e+38f

// ---------------- stage 1: pairwise partial mins ----------------

__global__ __launch_bounds__(BLK, 4)
void pair_part_kernel(const float* __restrict__ s1, const float* __restrict__ s2,
                      float* __restrict__ part /* [2][SPLIT][NPTS] */) {
    __shared__ float4 tile[CHUNK];

    const int tid = threadIdx.x;
    const int x   = blockIdx.x;
    const int y   = blockIdx.y;
    const int dir = blockIdx.z;
    const float* __restrict__ A = dir ? s2 : s1;
    const float* __restrict__ B = dir ? s1 : s2;

    const int obase = x * (BLK * P);
    const int cbase = y * CHUNK;

    // Stage inner tile once: float4(bx,by,bz,|b|^2).
    if (tid < CHUNK) {
        int g = cbase + tid;
        float bx = B[3 * g], by = B[3 * g + 1], bz = B[3 * g + 2];
        tile[tid] = make_float4(bx, by, bz, fmaf(bx, bx, fmaf(by, by, bz * bz)));
    }
    __syncthreads();

    float m2x[P], m2y[P], m2z[P], sa[P], mn[P];
    #pragma unroll
    for (int p = 0; p < P; ++p) {
        int i = obase + p * BLK + tid;
        float ax = A[3 * i], ay = A[3 * i + 1], az = A[3 * i + 2];
        sa[p]  = fmaf(ax, ax, fmaf(ay, ay, az * az));   // |a|^2
        m2x[p] = -(ax + ax); m2y[p] = -(ay + ay); m2z[p] = -(az + az);
        mn[p]  = FLTMAX;
    }

    // t = fma(-2ax,bx, fma(-2ay,by, fma(-2az,bz, |b|^2))) = d^2 - |a|^2.
    // 3 fma/pair + 0.5 min3/pair; one broadcast ds_read_b128 per 512 pairs.
    for (int j = 0; j < CHUNK; j += 4) {
        float4 b0 = tile[j], b1 = tile[j + 1], b2 = tile[j + 2], b3 = tile[j + 3];
        #pragma unroll
        for (int p = 0; p < P; ++p) {
            float t0 = fmaf(m2x[p], b0.x, fmaf(m2y[p], b0.y, fmaf(m2z[p], b0.z, b0.w)));
            float t1 = fmaf(m2x[p], b1.x, fmaf(m2y[p], b1.y, fmaf(m2z[p], b1.z, b1.w)));
            float t2 = fmaf(m2x[p], b2.x, fmaf(m2y[p], b2.y, fmaf(m2z[p], b2.z, b2.w)));
            float t3 = fmaf(m2x[p], b3.x, fmaf(m2y[p], b3.y, fmaf(m2z[p], b3.z, b3.w)));
            float u = fminf(fminf(mn[p], t0), t1);   // 2x v_min3_f32
            mn[p] = fminf(fminf(u, t2), t3);
        }
    }

    // Plain coalesced stores of partial min d^2 (clamped >= 0).
    float* dst = part + ((size_t)dir * SPLIT + y) * NPTS + obase;
    #pragma unroll
    for (int p = 0; p < P; ++p) {
        dst[p * BLK + tid] = fmaxf(sa[p] + mn[p], 0.0f);
    }
}

// ---------------- stage 2a: min over y within a slice ----------------

__global__ __launch_bounds__(BLK)
void reduce_slice_kernel(const float* __restrict__ part, float* __restrict__ part2) {
    const int tid = threadIdx.x;
    const int i   = blockIdx.x * BLK + tid;   // point index (64 blocks)
    const int sl  = blockIdx.y;               // slice 0..3
    const int dir = blockIdx.z;               // 0/1

    const float* rp = part + ((size_t)dir * SPLIT + sl * YSL) * NPTS + i;
    float m = FLTMAX;
    #pragma unroll 8
    for (int y = 0; y < YSL; ++y) m = fminf(m, rp[(size_t)y * NPTS]);

    part2[((size_t)dir * NSLICE + sl) * NPTS + i] = m;
}

// ---------------- stage 2b: final min, sqrt, block sums ----------------

__global__ __launch_bounds__(BLK)
void reduce_final_kernel(const float* __restrict__ part2, double* __restrict__ blocksum) {
    const int tid = threadIdx.x;
    const int i = blockIdx.x * BLK + tid;     // 64 blocks

    float r = FLTMAX, c = FLTMAX;
    #pragma unroll
    for (int sl = 0; sl < NSLICE; ++sl) {
        r = fminf(r, part2[(size_t)sl * NPTS + i]);
        c = fminf(c, part2[((size_t)NSLICE + sl) * NPTS + i]);
    }
    double s = (double)sqrtf(r) + (double)sqrtf(c);
    for (int off = 32; off > 0; off >>= 1) s += __shfl_down(s, off);
    __shared__ double w[4];
    if ((tid & 63) == 0) w[tid >> 6] = s;
    __syncthreads();
    if (tid == 0) blocksum[blockIdx.x] = w[0] + w[1] + w[2] + w[3];
}

__global__ void final_kernel(const double* __restrict__ blocksum, float* __restrict__ out) {
    const int lane = threadIdx.x;             // 64 threads
    double s = blocksum[lane];
    for (int off = 32; off > 0; off >>= 1) s += __shfl_down(s, off);
    if (lane == 0) out[0] = (float)(s / (double)NPTS);
}

// ---------------- fallback path (atomicMin, small ws) ----------------

__global__ __launch_bounds__(BLK)
void fb_init(unsigned int* rowmin, unsigned int* colmin) {
    int i = blockIdx.x * BLK + threadIdx.x;
    if (i < NPTS) { rowmin[i] = 0x7F7FFFFFu; colmin[i] = 0x7F7FFFFFu; }
}

__global__ __launch_bounds__(BLK, 4)
void fb_pair(const float* __restrict__ s1, const float* __restrict__ s2,
             unsigned int* __restrict__ rowmin, unsigned int* __restrict__ colmin) {
    __shared__ float4 tile[CHUNK];
    const int tid = threadIdx.x;
    const int dir = blockIdx.z;
    const float* __restrict__ A = dir ? s2 : s1;
    const float* __restrict__ B = dir ? s1 : s2;
    unsigned int* __restrict__ outmin = dir ? colmin : rowmin;
    const int obase = blockIdx.x * (BLK * P);
    const int cbase = blockIdx.y * CHUNK;

    if (tid < CHUNK) {
        int g = cbase + tid;
        float bx = B[3 * g], by = B[3 * g + 1], bz = B[3 * g + 2];
        tile[tid] = make_float4(bx, by, bz, fmaf(bx, bx, fmaf(by, by, bz * bz)));
    }
    __syncthreads();

    float m2x[P], m2y[P], m2z[P], sa[P], mn[P];
    #pragma unroll
    for (int p = 0; p < P; ++p) {
        int i = obase + p * BLK + tid;
        float ax = A[3 * i], ay = A[3 * i + 1], az = A[3 * i + 2];
        sa[p]  = fmaf(ax, ax, fmaf(ay, ay, az * az));
        m2x[p] = -(ax + ax); m2y[p] = -(ay + ay); m2z[p] = -(az + az);
        mn[p]  = FLTMAX;
    }
    for (int j = 0; j < CHUNK; j += 4) {
        float4 b0 = tile[j], b1 = tile[j + 1], b2 = tile[j + 2], b3 = tile[j + 3];
        #pragma unroll
        for (int p = 0; p < P; ++p) {
            float t0 = fmaf(m2x[p], b0.x, fmaf(m2y[p], b0.y, fmaf(m2z[p], b0.z, b0.w)));
            float t1 = fmaf(m2x[p], b1.x, fmaf(m2y[p], b1.y, fmaf(m2z[p], b1.z, b1.w)));
            float t2 = fmaf(m2x[p], b2.x, fmaf(m2y[p], b2.y, fmaf(m2z[p], b2.z, b2.w)));
            float t3 = fmaf(m2x[p], b3.x, fmaf(m2y[p], b3.y, fmaf(m2z[p], b3.z, b3.w)));
            float u = fminf(fminf(mn[p], t0), t1);
            mn[p] = fminf(fminf(u, t2), t3);
        }
    }
    #pragma unroll
    for (int p = 0; p < P; ++p) {
        float d2 = fmaxf(sa[p] + mn[p], 0.0f);
        atomicMin(&outmin[obase + p * BLK + tid], __float_as_uint(d2));
    }
}

__global__ __launch_bounds__(BLK)
void fb_reduce(const unsigned int* __restrict__ rowmin, const unsigned int* __restrict__ colmin,
               double* __restrict__ blocksum) {
    const int tid = threadIdx.x;
    const int i = blockIdx.x * BLK + tid;
    double s = (double)sqrtf(__uint_as_float(rowmin[i]))
             + (double)sqrtf(__uint_as_float(colmin[i]));
    for (int off = 32; off > 0; off >>= 1) s += __shfl_down(s, off);
    __shared__ double w[4];
    if ((tid & 63) == 0) w[tid >> 6] = s;
    __syncthreads();
    if (tid == 0) blocksum[blockIdx.x] = w[0] + w[1] + w[2] + w[3];
}

// ---------------- launch ----------------

extern "C" void kernel_launch(void* const* d_in, const int* in_sizes, int n_in,
                              void* d_out, int out_size, void* d_ws, size_t ws_size,
                              hipStream_t stream) {
    const float* s1 = (const float*)d_in[0];
    const float* s2 = (const float*)d_in[1];
    float* out = (float*)d_out;

    const size_t part_elems  = (size_t)2 * SPLIT * NPTS;     // 4M floats = 16.8 MB
    const size_t part2_elems = (size_t)2 * NSLICE * NPTS;    // 128K floats = 512 KB
    const size_t need = (part_elems + part2_elems) * sizeof(float) + 64 * sizeof(double);

    if (ws_size >= need) {
        float* part  = (float*)d_ws;
        float* part2 = part + part_elems;
        double* blocksum = (double*)(part2 + part2_elems);

        dim3 grid(XBLK, SPLIT, 2);                           // 8 x 128 x 2 = 2048
        pair_part_kernel<<<grid, BLK, 0, stream>>>(s1, s2, part);
        reduce_slice_kernel<<<dim3(NPTS / BLK, NSLICE, 2), BLK, 0, stream>>>(part, part2);
        reduce_final_kernel<<<NPTS / BLK, BLK, 0, stream>>>(part2, blocksum);
        final_kernel<<<1, 64, 0, stream>>>(blocksum, out);
    } else {
        unsigned int* rowmin = (unsigned int*)d_ws;
        unsigned int* colmin = rowmin + NPTS;
        double* blocksum = (double*)(colmin + NPTS);

        fb_init<<<NPTS / BLK, BLK, 0, stream>>>(rowmin, colmin);
        dim3 grid(XBLK, SPLIT, 2);
        fb_pair<<<grid, BLK, 0, stream>>>(s1, s2, rowmin, colmin);
        fb_reduce<<<NPTS / BLK, BLK, 0, stream>>>(rowmin, colmin, blocksum);
        final_kernel<<<1, 64, 0, stream>>>(blocksum, out);
    }
}